// Round 12
// baseline (112.553 us; speedup 1.0000x reference)
//
#include <hip/hip_runtime.h>

#define NROWS  8
#define NPIX   262144         // 512*512
#define K1_BPR 256            // compute: 1024 px/block, grid 2048
#define KF_BPR 8              // finish : 32768 px/block, grid 64
#define HB8    256            // 8-bit histogram bins per row
#define NSALT  16             // LDS histogram replication (bank-spread)
#define SSTRIDE 257           // copy stride: bank = (salt + bin) % 32

// monotonic float->uint map (ascending float == ascending uint)
__device__ __forceinline__ unsigned int fkey(float x){
  unsigned int u = __float_as_uint(x);
  return (u & 0x80000000u) ? ~u : (u | 0x80000000u);
}

// binary softmax with a single exp
__device__ __forceinline__ void softmax2(float a0, float a1,
    float& lp0, float& lp1, float& p0, float& p1){
  float d  = a1 - a0;
  float ad = -fabsf(d);
  float e  = __expf(ad);
  float s  = 1.0f + e;
  float ls = __logf(s);
  float rs = __builtin_amdgcn_rcpf(s);
  float lpM = -ls,  lpm = ad - ls;
  float pM  = rs,   pm  = e * rs;
  bool g = (d >= 0.0f);
  lp1 = g ? lpM : lpm;  lp0 = g ? lpm : lpM;
  p1  = g ? pM  : pm;   p0  = g ? pm  : pM;
}

__device__ __forceinline__ float focal2(float tt, float lp0, float lp1,
                                        float p0, float p1){
  float q1 = 1.0f - p1, q0 = 1.0f - p0;
  return -(tt * q1 * q1 * lp1) - ((1.0f - tt) * q0 * q0 * lp0);
}

__device__ __forceinline__ unsigned kTop(const float* frp){
  return (unsigned)((1.0 - (double)(*frp)) * (double)NPIX);   // 209715
}

// parallel 256-bin select (256 threads): returns (bin, kRem-within-bin)
__device__ __forceinline__ uint2 selectBinV(unsigned v, unsigned kRem,
    unsigned* cum, unsigned* res){
  const int t = threadIdx.x;
  cum[t] = v;
  if (t == 0){ res[0] = 255u; res[1] = kRem; }
  __syncthreads();
  unsigned run = v;
  #pragma unroll
  for (int off = 1; off < 256; off <<= 1){
    unsigned add = (t >= off) ? cum[t - off] : 0u;
    __syncthreads();
    run += add;
    cum[t] = run;
    __syncthreads();
  }
  unsigned inc = cum[t], exc = inc - v;
  if (exc < kRem && inc >= kRem) { res[0] = (unsigned)t; res[1] = kRem - exc; }
  __syncthreads();
  uint2 r = make_uint2(res[0], res[1]);
  __syncthreads();
  return r;
}

// loss compute + pack + lane-salted 256-bin LDS hist -> plain bhist store.
// Also resets the finish kernel's done-counter (stream order guarantees
// this lands before k_finish starts; kernel boundary = free coherence).
// Packed word: [31:20]=key12  [19]=target  [18:0]=l3 bits (exp8+man10, rnd)
__global__ __launch_bounds__(256) void k_compute(
    const float* __restrict__ in1, const float* __restrict__ in2,
    const float* __restrict__ in3, const int* __restrict__ tgt,
    const float* __restrict__ kdwp,
    unsigned int* __restrict__ packed, unsigned int* __restrict__ bhist,
    unsigned int* __restrict__ ctrl)
{
  __shared__ unsigned lh[NSALT * SSTRIDE];   // 16.4 KB salted histogram
  const int t = threadIdx.x;
  for (int i = t; i < NSALT * SSTRIDE; i += 256) lh[i] = 0;
  __syncthreads();

  const int blk   = blockIdx.x;
  const int row   = blk >> 8;                       // / K1_BPR
  const int chunk = (blk & (K1_BPR - 1)) * (NPIX / K1_BPR);
  const int base  = chunk + 4 * t;
  const float kdw = *kdwp;
  const float w1  = (float)(1.0 - (double)kdw);
  if (blk == 0 && t == 0) ctrl[0] = 0;              // reset done-counter

  const size_t ro2 = (size_t)row * 2 * NPIX;
  const size_t ro1 = (size_t)row * NPIX;

  float4 x10 = *(const float4*)(in1 + ro2 + base);
  float4 x11 = *(const float4*)(in1 + ro2 + NPIX + base);
  float4 x20 = *(const float4*)(in2 + ro2 + base);
  float4 x21 = *(const float4*)(in2 + ro2 + NPIX + base);
  float4 x30 = *(const float4*)(in3 + ro2 + base);
  float4 x31 = *(const float4*)(in3 + ro2 + NPIX + base);
  int4   tg  = *(const int4*)(tgt + ro1 + base);

  float a10[4] = {x10.x, x10.y, x10.z, x10.w};
  float a11[4] = {x11.x, x11.y, x11.z, x11.w};
  float a20[4] = {x20.x, x20.y, x20.z, x20.w};
  float a21[4] = {x21.x, x21.y, x21.z, x21.w};
  float a30[4] = {x30.x, x30.y, x30.z, x30.w};
  float a31[4] = {x31.x, x31.y, x31.z, x31.w};
  int   tgv[4] = {tg.x, tg.y, tg.z, tg.w};

  const int salt = (t & (NSALT - 1)) * SSTRIDE;
  unsigned pw[4];
  #pragma unroll
  for (int j = 0; j < 4; ++j){
    float tt = (float)tgv[j];
    float lp10, lp11, p10, p11; softmax2(a10[j], a11[j], lp10, lp11, p10, p11);
    float lp20, lp21, p20, p21; softmax2(a20[j], a21[j], lp20, lp21, p20, p21);
    float lp30, lp31, p30, p31; softmax2(a30[j], a31[j], lp30, lp31, p30, p31);
    float l1 = focal2(tt, lp10, lp11, p10, p11);
    float l2 = focal2(tt, lp20, lp21, p20, p21);
    float l3 = focal2(tt, lp30, lp31, p30, p31);
    float kdl12 = p10 * (lp10 - lp20) + p11 * (lp11 - lp21);
    float kdl21 = p20 * (lp20 - lp10) + p21 * (lp21 - lp11);
    float loss  = w1 * (l1 + l2 + l3) + kdw * (kdl12 + kdl21);
    unsigned k12 = fkey(loss) >> 20;
    // l3 >= 0: keep exp8+man10, round-to-nearest via +0x1000 before shift
    unsigned lb = __float_as_uint(l3) + 0x1000u;
    pw[j] = (k12 << 20) | (((unsigned)tgv[j]) << 19) | ((lb >> 13) & 0x7FFFFu);
    atomicAdd(&lh[salt + (k12 >> 4)], 1u);     // 1 salted LDS atomic / pixel
  }
  *(uint4*)(packed + ro1 + base) = make_uint4(pw[0], pw[1], pw[2], pw[3]);

  __syncthreads();
  // reduce 16 copies (conflict-free: bank = (c+t)%32) -> plain store
  unsigned v = 0;
  #pragma unroll
  for (int c = 0; c < NSALT; ++c) v += lh[c * SSTRIDE + t];
  bhist[(size_t)blk * HB8 + t] = v;
}

// ONE kernel for everything downstream (deletes 2 dispatch boundaries):
// 64 blocks, 8/row. Each block: row-hist sum (L2, redundant x8,
// deterministic) -> selectBinV -> collect its 32K-px slice -> publish
// partials -> last-arriver (64 release fences, ~25ns each per r8 data)
// resolves ties and reduces.
__global__ __launch_bounds__(256) void k_finish(
    const unsigned int* __restrict__ packed,
    const unsigned int* __restrict__ bhist,
    const float* __restrict__ frp,
    double* __restrict__ pB3, unsigned int* __restrict__ pBT,
    unsigned int* __restrict__ pAT, unsigned int* __restrict__ pSub,
    unsigned int* __restrict__ ctrl, float* __restrict__ out)
{
  __shared__ unsigned cum[256];
  __shared__ unsigned res[2];
  __shared__ unsigned s_cnt[4][16];
  __shared__ float    s_l3[4][16];
  __shared__ unsigned s_tg[4][16];
  __shared__ double wd[4];
  __shared__ int   wi[8];
  __shared__ unsigned lastFlag;
  __shared__ unsigned sub_cnt[NROWS][16];
  __shared__ double   sub_l3[NROWS][16];
  __shared__ unsigned sub_tg[NROWS][16];
  __shared__ double dd[12];
  const int t = threadIdx.x, lane = t & 63, wid = t >> 6;
  const int blk = blockIdx.x;
  const int row = blk >> 3;                   // / KF_BPR
  const int chunk = (blk & (KF_BPR - 1)) * (NPIX / KF_BPR);
  const size_t ro = (size_t)row * NPIX;
  const unsigned k0 = kTop(frp);

  if (t < 64){
    s_cnt[t >> 4][t & 15] = 0; s_l3[t >> 4][t & 15] = 0.0f;
    s_tg[t >> 4][t & 15] = 0;
  }

  // ---- row histogram sum over 256 block-hists (coalesced, L2) ----
  const unsigned* bh = bhist + (size_t)row * K1_BPR * HB8;
  unsigned v = 0;
  #pragma unroll 16
  for (int b = 0; b < K1_BPR; ++b) v += bh[b * HB8 + t];
  uint2 s0 = selectBinV(v, k0, cum, res);
  const unsigned T8 = s0.x, kRem = s0.y;

  // ---- collect this block's 32K-pixel slice ----
  double b3 = 0.0; int bt = 0, at = 0;
  for (int it = 0; it < 32; ++it){
    int base = chunk + it * 1024 + 4 * t;
    uint4 w = *(const uint4*)(packed + ro + base);
    unsigned a[4] = {w.x, w.y, w.z, w.w};
    #pragma unroll
    for (int j = 0; j < 4; ++j){
      unsigned k8 = a[j] >> 24;
      float l3 = __uint_as_float((a[j] & 0x7FFFFu) << 13);
      int   tv = (int)((a[j] >> 19) & 1u);
      at += tv;
      if (k8 < T8){ b3 += (double)l3; bt += tv; }
      else if (k8 == T8){
        unsigned sub = (a[j] >> 20) & 15u;     // key12 refinement
        atomicAdd(&s_cnt[wid][sub], 1u);       // per-wave copy: 4x less clash
        atomicAdd(&s_l3[wid][sub], l3);
        if (tv) atomicAdd(&s_tg[wid][sub], 1u);
      }
    }
  }
  #pragma unroll
  for (int o = 32; o; o >>= 1){
    b3 += __shfl_down(b3, o); bt += __shfl_down(bt, o); at += __shfl_down(at, o);
  }
  if (lane == 0){ wd[wid] = b3; wi[wid] = bt; wi[4 + wid] = at; }
  __syncthreads();
  if (t < 16){
    unsigned* ps = pSub + (size_t)blk * 48;
    ps[t]      = s_cnt[0][t] + s_cnt[1][t] + s_cnt[2][t] + s_cnt[3][t];
    float l    = s_l3[0][t] + s_l3[1][t] + s_l3[2][t] + s_l3[3][t];
    ps[16 + t] = __float_as_uint(l);
    ps[32 + t] = s_tg[0][t] + s_tg[1][t] + s_tg[2][t] + s_tg[3][t];
  }
  if (t == 0){
    pB3[blk] = wd[0] + wd[1] + wd[2] + wd[3];
    pBT[blk] = (unsigned)(wi[0] + wi[1] + wi[2] + wi[3]);
    pAT[blk] = (unsigned)(wi[4] + wi[5] + wi[6] + wi[7]);
  }
  __syncthreads();              // all stores issued + drained (vmcnt(0))
  if (t == 0){
    __threadfence();            // release partials (64 fences total: ~1.5us)
    unsigned old = atomicAdd(&ctrl[0], 1u);
    lastFlag = (old == NROWS * KF_BPR - 1) ? 1u : 0u;
  }
  __syncthreads();
  if (!lastFlag) return;
  __threadfence();              // acquire all partials

  // ---- last block: reduce sub stats per (row,sub) ----
  if (t < 128){
    int r = t >> 4, s = t & 15;
    unsigned c = 0, g = 0; double l = 0.0;
    #pragma unroll
    for (int b = 0; b < KF_BPR; ++b){
      const unsigned* ps = pSub + (size_t)(r * KF_BPR + b) * 48;
      c += ps[s];
      l += (double)__uint_as_float(ps[16 + s]);
      g += ps[32 + s];
    }
    sub_cnt[r][s] = c; sub_l3[r][s] = l; sub_tg[r][s] = g;
  }
  __syncthreads();

  // per-row tie resolution (16 sub-bins, frac-weighted crossing bin)
  double tie3 = 0.0, tieT = 0.0;
  if (t < NROWS){
    const int r = t;
    // recompute this row's kRem (only valid in this block for row==blk>>3;
    // redo scan per row): cheap serial pass over the row hist in scalar
    const unsigned* bh2 = bhist + (size_t)r * K1_BPR * HB8;
    // serial would be slow; instead reuse: all rows' kRem derived below
  }
  // compute each row's (T8,kRem) via 8 sequential parallel scans (all
  // 256 threads participate; ~1us total)
  __shared__ unsigned rowKrem[NROWS];
  __shared__ unsigned rowT8[NROWS];
  for (int r = 0; r < NROWS; ++r){
    const unsigned* bh2 = bhist + (size_t)r * K1_BPR * HB8;
    unsigned vv = 0;
    #pragma unroll 16
    for (int b = 0; b < K1_BPR; ++b) vv += bh2[b * HB8 + t];
    uint2 sr = selectBinV(vv, k0, cum, res);
    if (t == 0){ rowT8[r] = sr.x; rowKrem[r] = sr.y; }
  }
  __syncthreads();

  if (t < NROWS){
    const int r = t;
    const unsigned kR = rowKrem[r];
    unsigned cum2 = 0;
    for (int s2 = 0; s2 < 16; ++s2){
      unsigned c = sub_cnt[r][s2];
      if (c){
        unsigned take = 0;
        if (kR > cum2){
          unsigned avail = kR - cum2;
          take = (avail < c) ? avail : c;
        }
        if (take){
          double fr = (double)take / (double)c;
          tie3 += fr * sub_l3[r][s2];
          tieT += fr * (double)sub_tg[r][s2];
        }
        cum2 += c;
      }
    }
  }

  double S3 = tie3, ST = tieT, TT = 0.0;
  for (int i = t; i < NROWS * KF_BPR; i += 256){
    S3 += pB3[i]; ST += (double)pBT[i]; TT += (double)pAT[i];
  }
  #pragma unroll
  for (int o = 32; o; o >>= 1){
    S3 += __shfl_down(S3, o); ST += __shfl_down(ST, o); TT += __shfl_down(TT, o);
  }
  if (lane == 0){ dd[wid] = S3; dd[4 + wid] = ST; dd[8 + wid] = TT; }
  __syncthreads();
  if (t == 0){
    double s0 = dd[0] + dd[1] + dd[2] + dd[3];
    double s1 = dd[4] + dd[5] + dd[6] + dd[7];
    double st = dd[8] + dd[9] + dd[10] + dd[11];
    out[0] = (float)(s0 / ((double)NROWS * (double)k0));
    out[1] = (float)(s1 / st);
  }
}

extern "C" void kernel_launch(void* const* d_in, const int* in_sizes, int n_in,
                              void* d_out, int out_size, void* d_ws, size_t ws_size,
                              hipStream_t stream)
{
  const float* in1  = (const float*)d_in[0];
  const float* in2  = (const float*)d_in[1];
  const float* in3  = (const float*)d_in[2];
  const int*   tgt  = (const int*)d_in[3];
  const float* frp  = (const float*)d_in[4];
  const float* kdwp = (const float*)d_in[5];
  float* out = (float*)d_out;
  char*  ws  = (char*)d_ws;

  const size_t off_packed = 0;                                      // 8 MB
  const size_t off_bhist  = (size_t)NROWS * NPIX * 4;               // 2 MB
  const size_t off_ctrl   = off_bhist + (size_t)NROWS * K1_BPR * HB8 * 4;
  const size_t off_pB3    = (off_ctrl + 256 + 255) & ~(size_t)255;  // doubles
  const size_t off_pBT    = off_pB3 + (size_t)NROWS * KF_BPR * 8;
  const size_t off_pAT    = off_pBT + (size_t)NROWS * KF_BPR * 4;
  const size_t off_pSub   = off_pAT + (size_t)NROWS * KF_BPR * 4;

  unsigned int* packed = (unsigned int*)(ws + off_packed);
  unsigned int* bhist  = (unsigned int*)(ws + off_bhist);
  unsigned int* ctrl   = (unsigned int*)(ws + off_ctrl);
  double*       pB3    = (double*)(ws + off_pB3);
  unsigned int* pBT    = (unsigned int*)(ws + off_pBT);
  unsigned int* pAT    = (unsigned int*)(ws + off_pAT);
  unsigned int* pSub   = (unsigned int*)(ws + off_pSub);

  k_compute<<<NROWS * K1_BPR, 256, 0, stream>>>(in1, in2, in3, tgt, kdwp,
                                                packed, bhist, ctrl);
  k_finish<<<NROWS * KF_BPR, 256, 0, stream>>>(packed, bhist, frp,
                                               pB3, pBT, pAT, pSub, ctrl, out);
}

// Round 13
// 42.288 us; speedup vs baseline: 2.6616x; 2.6616x over previous
//
#include <hip/hip_runtime.h>

#define NROWS  8
#define NPIX   262144         // 512*512
#define K1_BPR 256            // compute: 1024 px/block, grid 2048
#define KC_BPR 128            // collect: 2048 px/block, grid 1024
#define HB8    256            // 8-bit histogram bins per row
#define NSALT  16             // LDS histogram replication (bank-spread)
#define SSTRIDE 257           // copy stride: bank = (salt + bin) % 32

// monotonic float->uint map (ascending float == ascending uint)
__device__ __forceinline__ unsigned int fkey(float x){
  unsigned int u = __float_as_uint(x);
  return (u & 0x80000000u) ? ~u : (u | 0x80000000u);
}

// binary softmax with a single exp
__device__ __forceinline__ void softmax2(float a0, float a1,
    float& lp0, float& lp1, float& p0, float& p1){
  float d  = a1 - a0;
  float ad = -fabsf(d);
  float e  = __expf(ad);
  float s  = 1.0f + e;
  float ls = __logf(s);
  float rs = __builtin_amdgcn_rcpf(s);
  float lpM = -ls,  lpm = ad - ls;
  float pM  = rs,   pm  = e * rs;
  bool g = (d >= 0.0f);
  lp1 = g ? lpM : lpm;  lp0 = g ? lpm : lpM;
  p1  = g ? pM  : pm;   p0  = g ? pm  : pM;
}

__device__ __forceinline__ float focal2(float tt, float lp0, float lp1,
                                        float p0, float p1){
  float q1 = 1.0f - p1, q0 = 1.0f - p0;
  return -(tt * q1 * q1 * lp1) - ((1.0f - tt) * q0 * q0 * lp0);
}

__device__ __forceinline__ unsigned kTop(const float* frp){
  return (unsigned)((1.0 - (double)(*frp)) * (double)NPIX);   // 209715
}

// parallel 256-bin select (256 threads): returns (bin, kRem-within-bin)
__device__ __forceinline__ uint2 selectBinV(unsigned v, unsigned kRem,
    unsigned* cum, unsigned* res){
  const int t = threadIdx.x;
  cum[t] = v;
  if (t == 0){ res[0] = 255u; res[1] = kRem; }
  __syncthreads();
  unsigned run = v;
  #pragma unroll
  for (int off = 1; off < 256; off <<= 1){
    unsigned add = (t >= off) ? cum[t - off] : 0u;
    __syncthreads();
    run += add;
    cum[t] = run;
    __syncthreads();
  }
  unsigned inc = cum[t], exc = inc - v;
  if (exc < kRem && inc >= kRem) { res[0] = (unsigned)t; res[1] = kRem - exc; }
  __syncthreads();
  uint2 r = make_uint2(res[0], res[1]);
  __syncthreads();
  return r;
}

// loss compute + pack + lane-salted 256-bin LDS hist -> u16-packed bhist
// (plain stores). Block 0 zeroes the downstream sub-stat accumulator; the
// kernel boundary orders it before k_collect's atomics (r8 lesson: never
// use in-kernel device fences; r12 lesson: never launch <1K-block kernels).
// Packed word: [31:20]=key12  [19]=target  [18:0]=l3 bits (exp8+man10, rnd)
__global__ __launch_bounds__(256) void k_compute(
    const float* __restrict__ in1, const float* __restrict__ in2,
    const float* __restrict__ in3, const int* __restrict__ tgt,
    const float* __restrict__ kdwp,
    unsigned int* __restrict__ packed, unsigned int* __restrict__ bhist16,
    unsigned int* __restrict__ gsub)
{
  __shared__ unsigned lh[NSALT * SSTRIDE];   // 16.4 KB salted histogram
  __shared__ unsigned lh2[HB8];
  const int t = threadIdx.x;
  for (int i = t; i < NSALT * SSTRIDE; i += 256) lh[i] = 0;

  const int blk   = blockIdx.x;
  const int row   = blk >> 8;                       // / K1_BPR
  const int chunk = (blk & (K1_BPR - 1)) * (NPIX / K1_BPR);
  const int base  = chunk + 4 * t;
  const float kdw = *kdwp;
  const float w1  = (float)(1.0 - (double)kdw);
  if (blk == 0){                                    // zero sub-stat acc
    for (int i = t; i < 3 * NROWS * 16; i += 256) gsub[i] = 0u;
  }
  __syncthreads();

  const size_t ro2 = (size_t)row * 2 * NPIX;
  const size_t ro1 = (size_t)row * NPIX;

  float4 x10 = *(const float4*)(in1 + ro2 + base);
  float4 x11 = *(const float4*)(in1 + ro2 + NPIX + base);
  float4 x20 = *(const float4*)(in2 + ro2 + base);
  float4 x21 = *(const float4*)(in2 + ro2 + NPIX + base);
  float4 x30 = *(const float4*)(in3 + ro2 + base);
  float4 x31 = *(const float4*)(in3 + ro2 + NPIX + base);
  int4   tg  = *(const int4*)(tgt + ro1 + base);

  float a10[4] = {x10.x, x10.y, x10.z, x10.w};
  float a11[4] = {x11.x, x11.y, x11.z, x11.w};
  float a20[4] = {x20.x, x20.y, x20.z, x20.w};
  float a21[4] = {x21.x, x21.y, x21.z, x21.w};
  float a30[4] = {x30.x, x30.y, x30.z, x30.w};
  float a31[4] = {x31.x, x31.y, x31.z, x31.w};
  int   tgv[4] = {tg.x, tg.y, tg.z, tg.w};

  const int salt = (t & (NSALT - 1)) * SSTRIDE;
  unsigned pw[4];
  #pragma unroll
  for (int j = 0; j < 4; ++j){
    float tt = (float)tgv[j];
    float lp10, lp11, p10, p11; softmax2(a10[j], a11[j], lp10, lp11, p10, p11);
    float lp20, lp21, p20, p21; softmax2(a20[j], a21[j], lp20, lp21, p20, p21);
    float lp30, lp31, p30, p31; softmax2(a30[j], a31[j], lp30, lp31, p30, p31);
    float l1 = focal2(tt, lp10, lp11, p10, p11);
    float l2 = focal2(tt, lp20, lp21, p20, p21);
    float l3 = focal2(tt, lp30, lp31, p30, p31);
    float kdl12 = p10 * (lp10 - lp20) + p11 * (lp11 - lp21);
    float kdl21 = p20 * (lp20 - lp10) + p21 * (lp21 - lp11);
    float loss  = w1 * (l1 + l2 + l3) + kdw * (kdl12 + kdl21);
    unsigned k12 = fkey(loss) >> 20;
    // l3 >= 0: keep exp8+man10, round-to-nearest via +0x1000 before shift
    unsigned lb = __float_as_uint(l3) + 0x1000u;
    pw[j] = (k12 << 20) | (((unsigned)tgv[j]) << 19) | ((lb >> 13) & 0x7FFFFu);
    atomicAdd(&lh[salt + (k12 >> 4)], 1u);     // 1 salted LDS atomic / pixel
  }
  *(uint4*)(packed + ro1 + base) = make_uint4(pw[0], pw[1], pw[2], pw[3]);

  __syncthreads();
  // reduce 16 copies (conflict-free: bank = (c+t)%32); pack u16 pairs
  unsigned v = 0;
  #pragma unroll
  for (int c = 0; c < NSALT; ++c) v += lh[c * SSTRIDE + t];
  lh2[t] = v;
  __syncthreads();
  if (t < HB8 / 2)
    bhist16[(size_t)blk * (HB8 / 2) + t] = lh2[2 * t] | (lh2[2 * t + 1] << 16);
}

// collect (1024 blocks): inline row-scan from u16 bhist (L2-resident),
// slice collection, per-wave LDS sub-stats -> 48 global atomics onto the
// pre-zeroed gsub; plain partial stores. No k_hist, no k_zero dispatch.
__global__ __launch_bounds__(256) void k_collect(
    const unsigned int* __restrict__ packed,
    const unsigned int* __restrict__ bhist16,
    const float* __restrict__ frp,
    float* __restrict__ pB3, unsigned int* __restrict__ pBT,
    unsigned int* __restrict__ pAT,
    unsigned int* __restrict__ gsub, unsigned int* __restrict__ selKrem)
{
  __shared__ unsigned cum[256];
  __shared__ unsigned res[2];
  __shared__ unsigned s_cnt[4][16];
  __shared__ float    s_l3[4][16];
  __shared__ unsigned s_tg[4][16];
  __shared__ float wf[4];
  __shared__ int   wi[8];
  const int t = threadIdx.x, lane = t & 63, wid = t >> 6;
  const int blk   = blockIdx.x;
  const int row   = blk >> 7;                       // / KC_BPR
  const int chunk = (blk & (KC_BPR - 1)) * (NPIX / KC_BPR);
  const size_t ro = (size_t)row * NPIX;
  if (t < 64){
    s_cnt[t >> 4][t & 15] = 0; s_l3[t >> 4][t & 15] = 0.0f;
    s_tg[t >> 4][t & 15] = 0;
  }

  // row histogram: sum bin t over 256 compute blocks (u16-packed words)
  const unsigned* bh = bhist16 + (size_t)row * K1_BPR * (HB8 / 2);
  const int wsel = t >> 1, sh = (t & 1) * 16;
  unsigned v = 0;
  #pragma unroll 16
  for (int b = 0; b < K1_BPR; ++b)
    v += (bh[b * (HB8 / 2) + wsel] >> sh) & 0xFFFFu;
  uint2 s0 = selectBinV(v, kTop(frp), cum, res);
  const unsigned T8 = s0.x;
  if (t == 0) selKrem[row] = s0.y;   // duplicate same-value store: benign

  float b3 = 0.0f; int bt = 0, at = 0;
  #pragma unroll
  for (int it = 0; it < 2; ++it){
    int base = chunk + it * 1024 + 4 * t;
    uint4 w = *(const uint4*)(packed + ro + base);
    unsigned a[4] = {w.x, w.y, w.z, w.w};
    #pragma unroll
    for (int j = 0; j < 4; ++j){
      unsigned k8 = a[j] >> 24;
      float l3 = __uint_as_float((a[j] & 0x7FFFFu) << 13);
      int   tv = (int)((a[j] >> 19) & 1u);
      at += tv;
      if (k8 < T8){ b3 += l3; bt += tv; }
      else if (k8 == T8){
        unsigned sub = (a[j] >> 20) & 15u;     // key12 refinement
        atomicAdd(&s_cnt[wid][sub], 1u);       // per-wave copy: 4x less clash
        atomicAdd(&s_l3[wid][sub], l3);
        if (tv) atomicAdd(&s_tg[wid][sub], 1u);
      }
    }
  }
  #pragma unroll
  for (int o = 32; o; o >>= 1){
    b3 += __shfl_down(b3, o); bt += __shfl_down(bt, o); at += __shfl_down(at, o);
  }
  if (lane == 0){ wf[wid] = b3; wi[wid] = bt; wi[4 + wid] = at; }
  __syncthreads();
  if (t < 16){
    unsigned c = s_cnt[0][t] + s_cnt[1][t] + s_cnt[2][t] + s_cnt[3][t];
    float    l = s_l3[0][t] + s_l3[1][t] + s_l3[2][t] + s_l3[3][t];
    unsigned g = s_tg[0][t] + s_tg[1][t] + s_tg[2][t] + s_tg[3][t];
    // gsub layout: [0]=cnt[8][16], [128]=l3(float)[8][16], [256]=tg[8][16]
    if (c) atomicAdd(&gsub[row * 16 + t], c);
    if (l != 0.0f) atomicAdd((float*)&gsub[128 + row * 16 + t], l);
    if (g) atomicAdd(&gsub[256 + row * 16 + t], g);
  }
  if (t == 0){
    pB3[blk] = wf[0] + wf[1] + wf[2] + wf[3];
    pBT[blk] = (unsigned)(wi[0] + wi[1] + wi[2] + wi[3]);
    pAT[blk] = (unsigned)(wi[4] + wi[5] + wi[6] + wi[7]);
  }
}

// single block, tiny: tie fractions from gsub + reduce 3x1024 partials
__global__ __launch_bounds__(256) void k_final(
    const unsigned int* __restrict__ selKrem, const float* __restrict__ frp,
    const unsigned int* __restrict__ gsub,
    const float* __restrict__ pB3, const unsigned int* __restrict__ pBT,
    const unsigned int* __restrict__ pAT, float* __restrict__ out)
{
  __shared__ unsigned sh_sub[3 * NROWS * 16];
  __shared__ double dd[12];
  const int t = threadIdx.x, lane = t & 63, wid = t >> 6;
  const unsigned k0 = kTop(frp);
  for (int i = t; i < 3 * NROWS * 16; i += 256) sh_sub[i] = gsub[i];
  __syncthreads();

  // per-row tie resolution (16 sub-bins, frac-weighted crossing bin)
  double tie3 = 0.0, tieT = 0.0;
  if (t < NROWS){
    const int r = t;
    const unsigned kRem = selKrem[r];
    unsigned cum2 = 0;
    for (int s2 = 0; s2 < 16; ++s2){
      unsigned c = sh_sub[r * 16 + s2];
      if (c){
        unsigned take = 0;
        if (kRem > cum2){
          unsigned avail = kRem - cum2;
          take = (avail < c) ? avail : c;
        }
        if (take){
          double fr = (double)take / (double)c;
          tie3 += fr * (double)__uint_as_float(sh_sub[128 + r * 16 + s2]);
          tieT += fr * (double)sh_sub[256 + r * 16 + s2];
        }
        cum2 += c;
      }
    }
  }

  double S3 = tie3, ST = tieT, TT = 0.0;
  for (int i = t; i < NROWS * KC_BPR; i += 256){
    S3 += (double)pB3[i]; ST += (double)pBT[i]; TT += (double)pAT[i];
  }
  #pragma unroll
  for (int o = 32; o; o >>= 1){
    S3 += __shfl_down(S3, o); ST += __shfl_down(ST, o); TT += __shfl_down(TT, o);
  }
  if (lane == 0){ dd[wid] = S3; dd[4 + wid] = ST; dd[8 + wid] = TT; }
  __syncthreads();
  if (t == 0){
    double s0 = dd[0] + dd[1] + dd[2] + dd[3];
    double s1 = dd[4] + dd[5] + dd[6] + dd[7];
    double st = dd[8] + dd[9] + dd[10] + dd[11];
    out[0] = (float)(s0 / ((double)NROWS * (double)k0));
    out[1] = (float)(s1 / st);
  }
}

extern "C" void kernel_launch(void* const* d_in, const int* in_sizes, int n_in,
                              void* d_out, int out_size, void* d_ws, size_t ws_size,
                              hipStream_t stream)
{
  const float* in1  = (const float*)d_in[0];
  const float* in2  = (const float*)d_in[1];
  const float* in3  = (const float*)d_in[2];
  const int*   tgt  = (const int*)d_in[3];
  const float* frp  = (const float*)d_in[4];
  const float* kdwp = (const float*)d_in[5];
  float* out = (float*)d_out;
  char*  ws  = (char*)d_ws;

  const size_t off_packed = 0;                                       // 8 MB
  const size_t off_bh16   = (size_t)NROWS * NPIX * 4;                // 1 MB
  const size_t off_gsub   = off_bh16 + (size_t)NROWS * K1_BPR * (HB8/2) * 4;
  const size_t off_selKr  = off_gsub + 3 * NROWS * 16 * 4;
  const size_t off_pB3    = (off_selKr + NROWS * 4 + 255) & ~(size_t)255;
  const size_t off_pBT    = off_pB3 + (size_t)NROWS * KC_BPR * 4;
  const size_t off_pAT    = off_pBT + (size_t)NROWS * KC_BPR * 4;

  unsigned int* packed = (unsigned int*)(ws + off_packed);
  unsigned int* bh16   = (unsigned int*)(ws + off_bh16);
  unsigned int* gsub   = (unsigned int*)(ws + off_gsub);
  unsigned int* selKr  = (unsigned int*)(ws + off_selKr);
  float*        pB3    = (float*)(ws + off_pB3);
  unsigned int* pBT    = (unsigned int*)(ws + off_pBT);
  unsigned int* pAT    = (unsigned int*)(ws + off_pAT);

  k_compute<<<NROWS * K1_BPR, 256, 0, stream>>>(in1, in2, in3, tgt, kdwp,
                                                packed, bh16, gsub);
  k_collect<<<NROWS * KC_BPR, 256, 0, stream>>>(packed, bh16, frp,
                                                pB3, pBT, pAT, gsub, selKr);
  k_final<<<1, 256, 0, stream>>>(selKr, frp, gsub, pB3, pBT, pAT, out);
}

// Round 14
// 34.247 us; speedup vs baseline: 3.2865x; 1.2348x over previous
//
#include <hip/hip_runtime.h>

#define NROWS  8
#define NPIX   262144         // 512*512
#define K1_BPR 256            // compute: 1024 px/block, grid 2048
#define KC_BPR 64             // collect: 4096 px/block, grid 512
#define HB8    256            // 8-bit histogram bins per row
#define NSALT  16             // LDS histogram replication (bank-spread)
#define SSTRIDE 257           // copy stride: bank = (salt + bin) % 32

// monotonic float->uint map (ascending float == ascending uint)
__device__ __forceinline__ unsigned int fkey(float x){
  unsigned int u = __float_as_uint(x);
  return (u & 0x80000000u) ? ~u : (u | 0x80000000u);
}

// binary softmax with a single exp
__device__ __forceinline__ void softmax2(float a0, float a1,
    float& lp0, float& lp1, float& p0, float& p1){
  float d  = a1 - a0;
  float ad = -fabsf(d);
  float e  = __expf(ad);
  float s  = 1.0f + e;
  float ls = __logf(s);
  float rs = __builtin_amdgcn_rcpf(s);
  float lpM = -ls,  lpm = ad - ls;
  float pM  = rs,   pm  = e * rs;
  bool g = (d >= 0.0f);
  lp1 = g ? lpM : lpm;  lp0 = g ? lpm : lpM;
  p1  = g ? pM  : pm;   p0  = g ? pm  : pM;
}

__device__ __forceinline__ float focal2(float tt, float lp0, float lp1,
                                        float p0, float p1){
  float q1 = 1.0f - p1, q0 = 1.0f - p0;
  return -(tt * q1 * q1 * lp1) - ((1.0f - tt) * q0 * q0 * lp0);
}

__device__ __forceinline__ unsigned kTop(const float* frp){
  return (unsigned)((1.0 - (double)(*frp)) * (double)NPIX);   // 209715
}

// parallel 256-bin select (256 threads): returns (bin, kRem-within-bin)
__device__ __forceinline__ uint2 selectBinV(unsigned v, unsigned kRem,
    unsigned* cum, unsigned* res){
  const int t = threadIdx.x;
  cum[t] = v;
  if (t == 0){ res[0] = 255u; res[1] = kRem; }
  __syncthreads();
  unsigned run = v;
  #pragma unroll
  for (int off = 1; off < 256; off <<= 1){
    unsigned add = (t >= off) ? cum[t - off] : 0u;
    __syncthreads();
    run += add;
    cum[t] = run;
    __syncthreads();
  }
  unsigned inc = cum[t], exc = inc - v;
  if (exc < kRem && inc >= kRem) { res[0] = (unsigned)t; res[1] = kRem - exc; }
  __syncthreads();
  uint2 r = make_uint2(res[0], res[1]);
  __syncthreads();
  return r;
}

// loss compute + pack + lane-salted 256-bin LDS hist -> u16-packed bhist
// (plain stores). Block 0 zeroes the downstream sub-stat accumulator; the
// kernel boundary orders it before k_collect's atomics (r8 lesson: never
// use in-kernel device fences; r12 lesson: never launch <1K-block kernels).
// Packed word: [31:20]=key12  [19]=target  [18:0]=l3 bits (exp8+man10, rnd)
__global__ __launch_bounds__(256) void k_compute(
    const float* __restrict__ in1, const float* __restrict__ in2,
    const float* __restrict__ in3, const int* __restrict__ tgt,
    const float* __restrict__ kdwp,
    unsigned int* __restrict__ packed, unsigned int* __restrict__ bhist16,
    unsigned int* __restrict__ gsub)
{
  __shared__ unsigned lh[NSALT * SSTRIDE];   // 16.4 KB salted histogram
  __shared__ unsigned lh2[HB8];
  const int t = threadIdx.x;
  for (int i = t; i < NSALT * SSTRIDE; i += 256) lh[i] = 0;

  const int blk   = blockIdx.x;
  const int row   = blk >> 8;                       // / K1_BPR
  const int chunk = (blk & (K1_BPR - 1)) * (NPIX / K1_BPR);
  const int base  = chunk + 4 * t;
  const float kdw = *kdwp;
  const float w1  = (float)(1.0 - (double)kdw);
  if (blk == 0){                                    // zero sub-stat acc
    for (int i = t; i < 3 * NROWS * 16; i += 256) gsub[i] = 0u;
  }
  __syncthreads();

  const size_t ro2 = (size_t)row * 2 * NPIX;
  const size_t ro1 = (size_t)row * NPIX;

  float4 x10 = *(const float4*)(in1 + ro2 + base);
  float4 x11 = *(const float4*)(in1 + ro2 + NPIX + base);
  float4 x20 = *(const float4*)(in2 + ro2 + base);
  float4 x21 = *(const float4*)(in2 + ro2 + NPIX + base);
  float4 x30 = *(const float4*)(in3 + ro2 + base);
  float4 x31 = *(const float4*)(in3 + ro2 + NPIX + base);
  int4   tg  = *(const int4*)(tgt + ro1 + base);

  float a10[4] = {x10.x, x10.y, x10.z, x10.w};
  float a11[4] = {x11.x, x11.y, x11.z, x11.w};
  float a20[4] = {x20.x, x20.y, x20.z, x20.w};
  float a21[4] = {x21.x, x21.y, x21.z, x21.w};
  float a30[4] = {x30.x, x30.y, x30.z, x30.w};
  float a31[4] = {x31.x, x31.y, x31.z, x31.w};
  int   tgv[4] = {tg.x, tg.y, tg.z, tg.w};

  const int salt = (t & (NSALT - 1)) * SSTRIDE;
  unsigned pw[4];
  #pragma unroll
  for (int j = 0; j < 4; ++j){
    float tt = (float)tgv[j];
    float lp10, lp11, p10, p11; softmax2(a10[j], a11[j], lp10, lp11, p10, p11);
    float lp20, lp21, p20, p21; softmax2(a20[j], a21[j], lp20, lp21, p20, p21);
    float lp30, lp31, p30, p31; softmax2(a30[j], a31[j], lp30, lp31, p30, p31);
    float l1 = focal2(tt, lp10, lp11, p10, p11);
    float l2 = focal2(tt, lp20, lp21, p20, p21);
    float l3 = focal2(tt, lp30, lp31, p30, p31);
    float kdl12 = p10 * (lp10 - lp20) + p11 * (lp11 - lp21);
    float kdl21 = p20 * (lp20 - lp10) + p21 * (lp21 - lp11);
    float loss  = w1 * (l1 + l2 + l3) + kdw * (kdl12 + kdl21);
    unsigned k12 = fkey(loss) >> 20;
    // l3 >= 0: keep exp8+man10, round-to-nearest via +0x1000 before shift
    unsigned lb = __float_as_uint(l3) + 0x1000u;
    pw[j] = (k12 << 20) | (((unsigned)tgv[j]) << 19) | ((lb >> 13) & 0x7FFFFu);
    atomicAdd(&lh[salt + (k12 >> 4)], 1u);     // 1 salted LDS atomic / pixel
  }
  *(uint4*)(packed + ro1 + base) = make_uint4(pw[0], pw[1], pw[2], pw[3]);

  __syncthreads();
  // reduce 16 copies (conflict-free: bank = (c+t)%32); pack u16 pairs
  unsigned v = 0;
  #pragma unroll
  for (int c = 0; c < NSALT; ++c) v += lh[c * SSTRIDE + t];
  lh2[t] = v;
  __syncthreads();
  if (t < HB8 / 2)
    bhist16[(size_t)blk * (HB8 / 2) + t] = lh2[2 * t] | (lh2[2 * t + 1] << 16);
}

// collect (512 blocks): COALESCED row-scan (r13's 256 scalar strided loads
// per thread -> 64 contiguous uint2 loads; wave w covers blocks w+4i,
// lane l owns bins 4l..4l+3), selectBinV, slice collection, per-wave LDS
// sub-stats -> 48 global atomics onto pre-zeroed gsub, plain partials.
__global__ __launch_bounds__(256) void k_collect(
    const unsigned int* __restrict__ packed,
    const unsigned int* __restrict__ bhist16,
    const float* __restrict__ frp,
    float* __restrict__ pB3, unsigned int* __restrict__ pBT,
    unsigned int* __restrict__ pAT,
    unsigned int* __restrict__ gsub, unsigned int* __restrict__ selKrem)
{
  __shared__ unsigned cum[256];
  __shared__ unsigned res[2];
  __shared__ unsigned lhw[4][HB8];
  __shared__ unsigned s_cnt[4][16];
  __shared__ float    s_l3[4][16];
  __shared__ unsigned s_tg[4][16];
  __shared__ float wf[4];
  __shared__ int   wi[8];
  const int t = threadIdx.x, lane = t & 63, wid = t >> 6;
  const int blk   = blockIdx.x;
  const int row   = blk >> 6;                       // / KC_BPR
  const int chunk = (blk & (KC_BPR - 1)) * (NPIX / KC_BPR);
  const size_t ro = (size_t)row * NPIX;
  if (t < 64){
    s_cnt[t >> 4][t & 15] = 0; s_l3[t >> 4][t & 15] = 0.0f;
    s_tg[t >> 4][t & 15] = 0;
  }

  // ---- coalesced row-histogram scan ----
  // wave wid sums compute-blocks b = wid + 4i; lane reads uint2 at word 2*lane
  const unsigned* bh = bhist16 + (size_t)row * K1_BPR * (HB8 / 2);
  unsigned s0a = 0, s1a = 0, s2a = 0, s3a = 0;
  #pragma unroll 8
  for (int i = 0; i < K1_BPR / 4; ++i){
    const unsigned* p = bh + (size_t)(wid + 4 * i) * (HB8 / 2) + 2 * lane;
    uint2 w2 = *(const uint2*)p;
    s0a += w2.x & 0xFFFFu; s1a += w2.x >> 16;
    s2a += w2.y & 0xFFFFu; s3a += w2.y >> 16;
  }
  *(uint4*)&lhw[wid][4 * lane] = make_uint4(s0a, s1a, s2a, s3a);
  __syncthreads();
  unsigned v = lhw[0][t] + lhw[1][t] + lhw[2][t] + lhw[3][t];

  uint2 s0 = selectBinV(v, kTop(frp), cum, res);
  const unsigned T8 = s0.x;
  if (t == 0) selKrem[row] = s0.y;   // duplicate same-value store: benign

  float b3 = 0.0f; int bt = 0, at = 0;
  #pragma unroll
  for (int it = 0; it < 4; ++it){
    int base = chunk + it * 1024 + 4 * t;
    uint4 w = *(const uint4*)(packed + ro + base);
    unsigned a[4] = {w.x, w.y, w.z, w.w};
    #pragma unroll
    for (int j = 0; j < 4; ++j){
      unsigned k8 = a[j] >> 24;
      float l3 = __uint_as_float((a[j] & 0x7FFFFu) << 13);
      int   tv = (int)((a[j] >> 19) & 1u);
      at += tv;
      if (k8 < T8){ b3 += l3; bt += tv; }
      else if (k8 == T8){
        unsigned sub = (a[j] >> 20) & 15u;     // key12 refinement
        atomicAdd(&s_cnt[wid][sub], 1u);       // per-wave copy: 4x less clash
        atomicAdd(&s_l3[wid][sub], l3);
        if (tv) atomicAdd(&s_tg[wid][sub], 1u);
      }
    }
  }
  #pragma unroll
  for (int o = 32; o; o >>= 1){
    b3 += __shfl_down(b3, o); bt += __shfl_down(bt, o); at += __shfl_down(at, o);
  }
  if (lane == 0){ wf[wid] = b3; wi[wid] = bt; wi[4 + wid] = at; }
  __syncthreads();
  if (t < 16){
    unsigned c = s_cnt[0][t] + s_cnt[1][t] + s_cnt[2][t] + s_cnt[3][t];
    float    l = s_l3[0][t] + s_l3[1][t] + s_l3[2][t] + s_l3[3][t];
    unsigned g = s_tg[0][t] + s_tg[1][t] + s_tg[2][t] + s_tg[3][t];
    // gsub layout: [0]=cnt[8][16], [128]=l3(float)[8][16], [256]=tg[8][16]
    if (c) atomicAdd(&gsub[row * 16 + t], c);
    if (l != 0.0f) atomicAdd((float*)&gsub[128 + row * 16 + t], l);
    if (g) atomicAdd(&gsub[256 + row * 16 + t], g);
  }
  if (t == 0){
    pB3[blk] = wf[0] + wf[1] + wf[2] + wf[3];
    pBT[blk] = (unsigned)(wi[0] + wi[1] + wi[2] + wi[3]);
    pAT[blk] = (unsigned)(wi[4] + wi[5] + wi[6] + wi[7]);
  }
}

// single block, tiny: tie fractions from gsub + reduce 3x512 partials
__global__ __launch_bounds__(256) void k_final(
    const unsigned int* __restrict__ selKrem, const float* __restrict__ frp,
    const unsigned int* __restrict__ gsub,
    const float* __restrict__ pB3, const unsigned int* __restrict__ pBT,
    const unsigned int* __restrict__ pAT, float* __restrict__ out)
{
  __shared__ unsigned sh_sub[3 * NROWS * 16];
  __shared__ double dd[12];
  const int t = threadIdx.x, lane = t & 63, wid = t >> 6;
  const unsigned k0 = kTop(frp);
  for (int i = t; i < 3 * NROWS * 16; i += 256) sh_sub[i] = gsub[i];
  __syncthreads();

  // per-row tie resolution (16 sub-bins, frac-weighted crossing bin)
  double tie3 = 0.0, tieT = 0.0;
  if (t < NROWS){
    const int r = t;
    const unsigned kRem = selKrem[r];
    unsigned cum2 = 0;
    for (int s2 = 0; s2 < 16; ++s2){
      unsigned c = sh_sub[r * 16 + s2];
      if (c){
        unsigned take = 0;
        if (kRem > cum2){
          unsigned avail = kRem - cum2;
          take = (avail < c) ? avail : c;
        }
        if (take){
          double fr = (double)take / (double)c;
          tie3 += fr * (double)__uint_as_float(sh_sub[128 + r * 16 + s2]);
          tieT += fr * (double)sh_sub[256 + r * 16 + s2];
        }
        cum2 += c;
      }
    }
  }

  double S3 = tie3, ST = tieT, TT = 0.0;
  for (int i = t; i < NROWS * KC_BPR; i += 256){
    S3 += (double)pB3[i]; ST += (double)pBT[i]; TT += (double)pAT[i];
  }
  #pragma unroll
  for (int o = 32; o; o >>= 1){
    S3 += __shfl_down(S3, o); ST += __shfl_down(ST, o); TT += __shfl_down(TT, o);
  }
  if (lane == 0){ dd[wid] = S3; dd[4 + wid] = ST; dd[8 + wid] = TT; }
  __syncthreads();
  if (t == 0){
    double s0 = dd[0] + dd[1] + dd[2] + dd[3];
    double s1 = dd[4] + dd[5] + dd[6] + dd[7];
    double st = dd[8] + dd[9] + dd[10] + dd[11];
    out[0] = (float)(s0 / ((double)NROWS * (double)k0));
    out[1] = (float)(s1 / st);
  }
}

extern "C" void kernel_launch(void* const* d_in, const int* in_sizes, int n_in,
                              void* d_out, int out_size, void* d_ws, size_t ws_size,
                              hipStream_t stream)
{
  const float* in1  = (const float*)d_in[0];
  const float* in2  = (const float*)d_in[1];
  const float* in3  = (const float*)d_in[2];
  const int*   tgt  = (const int*)d_in[3];
  const float* frp  = (const float*)d_in[4];
  const float* kdwp = (const float*)d_in[5];
  float* out = (float*)d_out;
  char*  ws  = (char*)d_ws;

  const size_t off_packed = 0;                                       // 8 MB
  const size_t off_bh16   = (size_t)NROWS * NPIX * 4;                // 1 MB
  const size_t off_gsub   = off_bh16 + (size_t)NROWS * K1_BPR * (HB8/2) * 4;
  const size_t off_selKr  = off_gsub + 3 * NROWS * 16 * 4;
  const size_t off_pB3    = (off_selKr + NROWS * 4 + 255) & ~(size_t)255;
  const size_t off_pBT    = off_pB3 + (size_t)NROWS * KC_BPR * 4;
  const size_t off_pAT    = off_pBT + (size_t)NROWS * KC_BPR * 4;

  unsigned int* packed = (unsigned int*)(ws + off_packed);
  unsigned int* bh16   = (unsigned int*)(ws + off_bh16);
  unsigned int* gsub   = (unsigned int*)(ws + off_gsub);
  unsigned int* selKr  = (unsigned int*)(ws + off_selKr);
  float*        pB3    = (float*)(ws + off_pB3);
  unsigned int* pBT    = (unsigned int*)(ws + off_pBT);
  unsigned int* pAT    = (unsigned int*)(ws + off_pAT);

  k_compute<<<NROWS * K1_BPR, 256, 0, stream>>>(in1, in2, in3, tgt, kdwp,
                                                packed, bh16, gsub);
  k_collect<<<NROWS * KC_BPR, 256, 0, stream>>>(packed, bh16, frp,
                                                pB3, pBT, pAT, gsub, selKr);
  k_final<<<1, 256, 0, stream>>>(selKr, frp, gsub, pB3, pBT, pAT, out);
}

// Round 15
// 32.516 us; speedup vs baseline: 3.4615x; 1.0532x over previous
//
#include <hip/hip_runtime.h>

#define NROWS  8
#define NPIX   262144         // 512*512
#define K1_BPR 256            // compute: 1024 px/block, grid 2048
#define KC_BPR 64             // collect: 4096 px/block, grid 512
#define HB8    256            // 8-bit histogram bins per row
#define NSALT  16             // LDS histogram replication (bank-spread)
#define SSTRIDE 257           // copy stride: bank = (salt + bin) % 32

// monotonic float->uint map (ascending float == ascending uint)
__device__ __forceinline__ unsigned int fkey(float x){
  unsigned int u = __float_as_uint(x);
  return (u & 0x80000000u) ? ~u : (u | 0x80000000u);
}

// binary softmax with a single exp
__device__ __forceinline__ void softmax2(float a0, float a1,
    float& lp0, float& lp1, float& p0, float& p1){
  float d  = a1 - a0;
  float ad = -fabsf(d);
  float e  = __expf(ad);
  float s  = 1.0f + e;
  float ls = __logf(s);
  float rs = __builtin_amdgcn_rcpf(s);
  float lpM = -ls,  lpm = ad - ls;
  float pM  = rs,   pm  = e * rs;
  bool g = (d >= 0.0f);
  lp1 = g ? lpM : lpm;  lp0 = g ? lpm : lpM;
  p1  = g ? pM  : pm;   p0  = g ? pm  : pM;
}

__device__ __forceinline__ float focal2(float tt, float lp0, float lp1,
                                        float p0, float p1){
  float q1 = 1.0f - p1, q0 = 1.0f - p0;
  return -(tt * q1 * q1 * lp1) - ((1.0f - tt) * q0 * q0 * lp0);
}

__device__ __forceinline__ unsigned kTop(const float* frp){
  return (unsigned)((1.0 - (double)(*frp)) * (double)NPIX);   // 209715
}

// loss compute + pack + lane-salted 256-bin LDS hist -> u16-packed bhist
// (plain stores). Block 0 zeroes the downstream sub-stat accumulator; the
// kernel boundary orders it before k_collect's atomics (r8 lesson: never
// use in-kernel device fences; r12 lesson: never launch <1K-block kernels).
// Packed word: [31:20]=key12  [19]=target  [18:0]=l3 bits (exp8+man10, rnd)
__global__ __launch_bounds__(256) void k_compute(
    const float* __restrict__ in1, const float* __restrict__ in2,
    const float* __restrict__ in3, const int* __restrict__ tgt,
    const float* __restrict__ kdwp,
    unsigned int* __restrict__ packed, unsigned int* __restrict__ bhist16,
    unsigned int* __restrict__ gsub)
{
  __shared__ unsigned lh[NSALT * SSTRIDE];   // 16.4 KB salted histogram
  __shared__ unsigned lh2[HB8];
  const int t = threadIdx.x;
  for (int i = t; i < NSALT * SSTRIDE; i += 256) lh[i] = 0;

  const int blk   = blockIdx.x;
  const int row   = blk >> 8;                       // / K1_BPR
  const int chunk = (blk & (K1_BPR - 1)) * (NPIX / K1_BPR);
  const int base  = chunk + 4 * t;
  const float kdw = *kdwp;
  const float w1  = (float)(1.0 - (double)kdw);
  if (blk == 0){                                    // zero sub-stat acc
    for (int i = t; i < 3 * NROWS * 16; i += 256) gsub[i] = 0u;
  }
  __syncthreads();

  const size_t ro2 = (size_t)row * 2 * NPIX;
  const size_t ro1 = (size_t)row * NPIX;

  float4 x10 = *(const float4*)(in1 + ro2 + base);
  float4 x11 = *(const float4*)(in1 + ro2 + NPIX + base);
  float4 x20 = *(const float4*)(in2 + ro2 + base);
  float4 x21 = *(const float4*)(in2 + ro2 + NPIX + base);
  float4 x30 = *(const float4*)(in3 + ro2 + base);
  float4 x31 = *(const float4*)(in3 + ro2 + NPIX + base);
  int4   tg  = *(const int4*)(tgt + ro1 + base);

  float a10[4] = {x10.x, x10.y, x10.z, x10.w};
  float a11[4] = {x11.x, x11.y, x11.z, x11.w};
  float a20[4] = {x20.x, x20.y, x20.z, x20.w};
  float a21[4] = {x21.x, x21.y, x21.z, x21.w};
  float a30[4] = {x30.x, x30.y, x30.z, x30.w};
  float a31[4] = {x31.x, x31.y, x31.z, x31.w};
  int   tgv[4] = {tg.x, tg.y, tg.z, tg.w};

  const int salt = (t & (NSALT - 1)) * SSTRIDE;
  unsigned pw[4];
  #pragma unroll
  for (int j = 0; j < 4; ++j){
    float tt = (float)tgv[j];
    float lp10, lp11, p10, p11; softmax2(a10[j], a11[j], lp10, lp11, p10, p11);
    float lp20, lp21, p20, p21; softmax2(a20[j], a21[j], lp20, lp21, p20, p21);
    float lp30, lp31, p30, p31; softmax2(a30[j], a31[j], lp30, lp31, p30, p31);
    float l1 = focal2(tt, lp10, lp11, p10, p11);
    float l2 = focal2(tt, lp20, lp21, p20, p21);
    float l3 = focal2(tt, lp30, lp31, p30, p31);
    float kdl12 = p10 * (lp10 - lp20) + p11 * (lp11 - lp21);
    float kdl21 = p20 * (lp20 - lp10) + p21 * (lp21 - lp11);
    float loss  = w1 * (l1 + l2 + l3) + kdw * (kdl12 + kdl21);
    unsigned k12 = fkey(loss) >> 20;
    // l3 >= 0: keep exp8+man10, round-to-nearest via +0x1000 before shift
    unsigned lb = __float_as_uint(l3) + 0x1000u;
    pw[j] = (k12 << 20) | (((unsigned)tgv[j]) << 19) | ((lb >> 13) & 0x7FFFFu);
    atomicAdd(&lh[salt + (k12 >> 4)], 1u);     // 1 salted LDS atomic / pixel
  }
  *(uint4*)(packed + ro1 + base) = make_uint4(pw[0], pw[1], pw[2], pw[3]);

  __syncthreads();
  // reduce 16 copies (conflict-free: bank = (c+t)%32); pack u16 pairs
  unsigned v = 0;
  #pragma unroll
  for (int c = 0; c < NSALT; ++c) v += lh[c * SSTRIDE + t];
  lh2[t] = v;
  __syncthreads();
  if (t < HB8 / 2)
    bhist16[(size_t)blk * (HB8 / 2) + t] = lh2[2 * t] | (lh2[2 * t + 1] << 16);
}

// collect (512 blocks): coalesced row-scan + shfl-based bin select
// (3 barriers vs r14's 17) + ATOMIC-FREE per-thread-slot sub-stats
// (r14's tie-bin LDS atomics serialized: tie bin holds 10-20% of pixels,
// ~450 same-address atomics/wave). Plain stores for partials.
__global__ __launch_bounds__(256) void k_collect(
    const unsigned int* __restrict__ packed,
    const unsigned int* __restrict__ bhist16,
    const float* __restrict__ frp,
    float* __restrict__ pB3, unsigned int* __restrict__ pBT,
    unsigned int* __restrict__ pAT,
    unsigned int* __restrict__ gsub, unsigned int* __restrict__ selKrem)
{
  __shared__ unsigned lhw[4][HB8];     // 4 KB scan staging (reused)
  __shared__ unsigned ct[16 * 256];    // 16 KB: cnt | tg<<16, slot [sub][t]
  __shared__ float    sl[16 * 256];    // 16 KB: l3 sum,      slot [sub][t]
  __shared__ unsigned wsum[4];
  __shared__ unsigned res[2];
  __shared__ float wf[4];
  __shared__ int   wi[8];
  const int t = threadIdx.x, lane = t & 63, wid = t >> 6;
  const int blk   = blockIdx.x;
  const int row   = blk >> 6;                       // / KC_BPR
  const int chunk = (blk & (KC_BPR - 1)) * (NPIX / KC_BPR);
  const size_t ro = (size_t)row * NPIX;

  // zero per-thread sub-stat slots (conflict-free)
  #pragma unroll
  for (int i = 0; i < 16; ++i){ ct[i * 256 + t] = 0u; sl[i * 256 + t] = 0.0f; }

  // ---- coalesced row-histogram scan ----
  // wave wid sums compute-blocks b = wid + 4i; lane reads uint2 at word 2*lane
  const unsigned* bh = bhist16 + (size_t)row * K1_BPR * (HB8 / 2);
  unsigned s0a = 0, s1a = 0, s2a = 0, s3a = 0;
  #pragma unroll 8
  for (int i = 0; i < K1_BPR / 4; ++i){
    const unsigned* p = bh + (size_t)(wid + 4 * i) * (HB8 / 2) + 2 * lane;
    uint2 w2 = *(const uint2*)p;
    s0a += w2.x & 0xFFFFu; s1a += w2.x >> 16;
    s2a += w2.y & 0xFFFFu; s3a += w2.y >> 16;
  }
  *(uint4*)&lhw[wid][4 * lane] = make_uint4(s0a, s1a, s2a, s3a);
  const unsigned k0 = kTop(frp);
  if (t == 0){ res[0] = 255u; res[1] = k0; }
  __syncthreads();                                       // barrier 1
  unsigned v = lhw[0][t] + lhw[1][t] + lhw[2][t] + lhw[3][t];

  // wave-level inclusive scan (shfl, no barriers) + cross-wave combine
  unsigned run = v;
  #pragma unroll
  for (int o = 1; o < 64; o <<= 1){
    unsigned n = __shfl_up(run, o);
    if (lane >= o) run += n;
  }
  if (lane == 63) wsum[wid] = run;
  __syncthreads();                                       // barrier 2
  unsigned pre = 0;
  for (int w = 0; w < 4; ++w) if (w < wid) pre += wsum[w];
  unsigned inc = run + pre, exc = inc - v;
  if (exc < k0 && inc >= k0){ res[0] = (unsigned)t; res[1] = k0 - exc; }
  __syncthreads();                                       // barrier 3
  const unsigned T8 = res[0];
  if (t == 0) selKrem[row] = res[1];  // duplicate same-value store: benign

  float b3 = 0.0f; int bt = 0, at = 0;
  #pragma unroll
  for (int it = 0; it < 4; ++it){
    int base = chunk + it * 1024 + 4 * t;
    uint4 w = *(const uint4*)(packed + ro + base);
    unsigned a[4] = {w.x, w.y, w.z, w.w};
    #pragma unroll
    for (int j = 0; j < 4; ++j){
      unsigned k8 = a[j] >> 24;
      float l3 = __uint_as_float((a[j] & 0x7FFFFu) << 13);
      unsigned tv = (a[j] >> 19) & 1u;
      at += (int)tv;
      if (k8 < T8){ b3 += l3; bt += (int)tv; }
      else if (k8 == T8){
        // plain conflict-free LDS RMW into this thread's private slot
        int idx = (int)((a[j] >> 20) & 15u) * 256 + t;
        ct[idx] += 1u | (tv << 16);
        sl[idx] += l3;
      }
    }
  }
  #pragma unroll
  for (int o = 32; o; o >>= 1){
    b3 += __shfl_down(b3, o); bt += __shfl_down(bt, o); at += __shfl_down(at, o);
  }
  if (lane == 0){ wf[wid] = b3; wi[wid] = bt; wi[4 + wid] = at; }
  __syncthreads();                                       // barrier 4

  // reduce per-thread slots: thread t -> sub = t>>4, slots (t&15)*16 + i
  {
    int s = t >> 4, c0 = (t & 15) * 16;
    unsigned pc = 0; float pl = 0.0f;
    #pragma unroll
    for (int i = 0; i < 16; ++i){
      pc += ct[s * 256 + c0 + i];
      pl += sl[s * 256 + c0 + i];
    }
    lhw[0][t] = pc;
    ((float*)lhw[1])[t] = pl;
  }
  __syncthreads();                                       // barrier 5
  if (t < 16){
    unsigned cc = 0; float ll = 0.0f;
    #pragma unroll
    for (int i = 0; i < 16; ++i){
      cc += lhw[0][t * 16 + i];
      ll += ((float*)lhw[1])[t * 16 + i];
    }
    unsigned cnt = cc & 0xFFFFu, tgc = cc >> 16;
    // gsub layout: [0]=cnt[8][16], [128]=l3(float)[8][16], [256]=tg[8][16]
    if (cnt) atomicAdd(&gsub[row * 16 + t], cnt);
    if (ll != 0.0f) atomicAdd((float*)&gsub[128 + row * 16 + t], ll);
    if (tgc) atomicAdd(&gsub[256 + row * 16 + t], tgc);
  }
  if (t == 0){
    pB3[blk] = wf[0] + wf[1] + wf[2] + wf[3];
    pBT[blk] = (unsigned)(wi[0] + wi[1] + wi[2] + wi[3]);
    pAT[blk] = (unsigned)(wi[4] + wi[5] + wi[6] + wi[7]);
  }
}

// single block, tiny: tie fractions from gsub + reduce 3x512 partials
__global__ __launch_bounds__(256) void k_final(
    const unsigned int* __restrict__ selKrem, const float* __restrict__ frp,
    const unsigned int* __restrict__ gsub,
    const float* __restrict__ pB3, const unsigned int* __restrict__ pBT,
    const unsigned int* __restrict__ pAT, float* __restrict__ out)
{
  __shared__ unsigned sh_sub[3 * NROWS * 16];
  __shared__ double dd[12];
  const int t = threadIdx.x, lane = t & 63, wid = t >> 6;
  const unsigned k0 = kTop(frp);
  for (int i = t; i < 3 * NROWS * 16; i += 256) sh_sub[i] = gsub[i];
  __syncthreads();

  // per-row tie resolution (16 sub-bins, frac-weighted crossing bin)
  double tie3 = 0.0, tieT = 0.0;
  if (t < NROWS){
    const int r = t;
    const unsigned kRem = selKrem[r];
    unsigned cum2 = 0;
    for (int s2 = 0; s2 < 16; ++s2){
      unsigned c = sh_sub[r * 16 + s2];
      if (c){
        unsigned take = 0;
        if (kRem > cum2){
          unsigned avail = kRem - cum2;
          take = (avail < c) ? avail : c;
        }
        if (take){
          double fr = (double)take / (double)c;
          tie3 += fr * (double)__uint_as_float(sh_sub[128 + r * 16 + s2]);
          tieT += fr * (double)sh_sub[256 + r * 16 + s2];
        }
        cum2 += c;
      }
    }
  }

  double S3 = tie3, ST = tieT, TT = 0.0;
  for (int i = t; i < NROWS * KC_BPR; i += 256){
    S3 += (double)pB3[i]; ST += (double)pBT[i]; TT += (double)pAT[i];
  }
  #pragma unroll
  for (int o = 32; o; o >>= 1){
    S3 += __shfl_down(S3, o); ST += __shfl_down(ST, o); TT += __shfl_down(TT, o);
  }
  if (lane == 0){ dd[wid] = S3; dd[4 + wid] = ST; dd[8 + wid] = TT; }
  __syncthreads();
  if (t == 0){
    double s0 = dd[0] + dd[1] + dd[2] + dd[3];
    double s1 = dd[4] + dd[5] + dd[6] + dd[7];
    double st = dd[8] + dd[9] + dd[10] + dd[11];
    out[0] = (float)(s0 / ((double)NROWS * (double)k0));
    out[1] = (float)(s1 / st);
  }
}

extern "C" void kernel_launch(void* const* d_in, const int* in_sizes, int n_in,
                              void* d_out, int out_size, void* d_ws, size_t ws_size,
                              hipStream_t stream)
{
  const float* in1  = (const float*)d_in[0];
  const float* in2  = (const float*)d_in[1];
  const float* in3  = (const float*)d_in[2];
  const int*   tgt  = (const int*)d_in[3];
  const float* frp  = (const float*)d_in[4];
  const float* kdwp = (const float*)d_in[5];
  float* out = (float*)d_out;
  char*  ws  = (char*)d_ws;

  const size_t off_packed = 0;                                       // 8 MB
  const size_t off_bh16   = (size_t)NROWS * NPIX * 4;                // 1 MB
  const size_t off_gsub   = off_bh16 + (size_t)NROWS * K1_BPR * (HB8/2) * 4;
  const size_t off_selKr  = off_gsub + 3 * NROWS * 16 * 4;
  const size_t off_pB3    = (off_selKr + NROWS * 4 + 255) & ~(size_t)255;
  const size_t off_pBT    = off_pB3 + (size_t)NROWS * KC_BPR * 4;
  const size_t off_pAT    = off_pBT + (size_t)NROWS * KC_BPR * 4;

  unsigned int* packed = (unsigned int*)(ws + off_packed);
  unsigned int* bh16   = (unsigned int*)(ws + off_bh16);
  unsigned int* gsub   = (unsigned int*)(ws + off_gsub);
  unsigned int* selKr  = (unsigned int*)(ws + off_selKr);
  float*        pB3    = (float*)(ws + off_pB3);
  unsigned int* pBT    = (unsigned int*)(ws + off_pBT);
  unsigned int* pAT    = (unsigned int*)(ws + off_pAT);

  k_compute<<<NROWS * K1_BPR, 256, 0, stream>>>(in1, in2, in3, tgt, kdwp,
                                                packed, bh16, gsub);
  k_collect<<<NROWS * KC_BPR, 256, 0, stream>>>(packed, bh16, frp,
                                                pB3, pBT, pAT, gsub, selKr);
  k_final<<<1, 256, 0, stream>>>(selKr, frp, gsub, pB3, pBT, pAT, out);
}